// Round 7
// baseline (430.526 us; speedup 1.0000x reference)
//
#include <hip/hip_runtime.h>

typedef unsigned long long u64;
typedef unsigned int u32;
typedef unsigned short u16;

#define MSORT 4096     // sort capacity (power of 2); K ~2000 for this input
#define TPB   256
#define BOXCAP 3648    // 57*64 boxes staged in LDS (57 KB)
#define RSLOT_W 10     // register slots per wave (covers K <= 2560 all-register)
#define KPC   300      // kept per class (only top-300/class can reach global top-300)
#define SELCAP 1024
#define RPT  (MSORT / TPB)

// LDS layout (bytes):
//  [0,     58368)  float4 boxes[3648]  (aliased: u64 sortbuf[4096] = 32 KB during sort)
//  [58368, 58976)  u16 keptR[304]      (kept ranks, in order — epilogue)
//  [58976, 58988)  u32 ctl[3] = {cntK, activeW, doneF}
//  [58992, 63856)  float4 pubBox[304]  (published kept boxes for passive waves)
//  [63856, 63860)  int cntS

#define WG_SCOPE __HIP_MEMORY_SCOPE_WORKGROUP

// sweep of this wave's own slots: 10 register slots (unconditional — bits
// beyond own range land in private sup and are never scanned) + LDS tail
// (only when K > 2560). Pure VALU, dependence-free, exact numpy arithmetic.
template<bool GE>
__device__ __forceinline__ u64 sweep_own(
    float4 bi, float area_i, const float4 (&breg)[RSLOT_W],
    const float (&areaj)[RSLOT_W], const float4* __restrict__ boxesLds,
    int base, int nslots, int lane, double B)
{
    u64 ns = 0;
    #pragma unroll
    for (int t = 0; t < RSLOT_W; t++) {
        float4 bj = breg[t];
        float ix1 = fmaxf(bi.x, bj.x), iy1 = fmaxf(bi.y, bj.y);
        float ix2 = fminf(bi.z, bj.z), iy2 = fminf(bi.w, bj.w);
        float iw  = fmaxf(__fsub_rn(ix2, ix1), 0.0f);
        float ih  = fmaxf(__fsub_rn(iy2, iy1), 0.0f);
        float inter = __fmul_rn(iw, ih);
        float uni   = __fsub_rn(__fadd_rn(area_i, areaj[t]), inter);
        bool c = GE ? ((double)inter >= B * (double)uni)
                    : ((double)inter >  B * (double)uni);
        ns |= ((u64)c) << (base + t);
    }
    for (int t = RSLOT_W; t < nslots; t++) {   // K > 2560 only
        float4 bj = boxesLds[((base + t) << 6) | lane];
        float ix1 = fmaxf(bi.x, bj.x), iy1 = fmaxf(bi.y, bj.y);
        float ix2 = fminf(bi.z, bj.z), iy2 = fminf(bi.w, bj.w);
        float iw  = fmaxf(__fsub_rn(ix2, ix1), 0.0f);
        float ih  = fmaxf(__fsub_rn(iy2, iy1), 0.0f);
        float inter = __fmul_rn(iw, ih);
        float area_j = __fmul_rn(__fsub_rn(bj.z, bj.x), __fsub_rn(bj.w, bj.y));
        float uni   = __fsub_rn(__fadd_rn(area_i, area_j), inter);
        bool c = GE ? ((double)inter >= B * (double)uni)
                    : ((double)inter >  B * (double)uni);
        ns |= ((u64)c) << (base + t);
    }
    return ns;
}

// Barrier-free producer/consumer greedy NMS. Wave w owns contiguous slots
// [base,end). The wave whose range contains the (monotone) scan cursor is
// "active": it scans its own bits (complete for its range), decides kept
// boxes, publishes them (pubBox/keptR + release cntK). Passive waves
// acquire cntK, sweep each published box over their own range. Handoff via
// release activeW; termination via doneF.
template<bool GE>
__device__ __forceinline__ void greedy_nms(
    const float4* __restrict__ boxesLds, u16* __restrict__ keptR,
    float4* __restrict__ pubBox, u32* __restrict__ ctl,
    int K, int smax, double B, int lane, int wave)
{
    const int SW   = (smax + 3) >> 2;
    const int base = (wave * SW < smax) ? wave * SW : smax;
    const int end  = (base + SW < smax) ? base + SW : smax;
    const int nslots = end - base;

    float4 breg[RSLOT_W];
    float  areaj[RSLOT_W];
    #pragma unroll
    for (int t = 0; t < RSLOT_W; t++) {
        float4 b = boxesLds[((base + t) << 6) | lane];
        breg[t] = b;
        areaj[t] = __fmul_rn(__fsub_rn(b.z, b.x), __fsub_rn(b.w, b.y));
    }

    u64 sup;
    {
        int t = (lane < K) ? ((K - lane + 63) >> 6) : 0;  // valid slots for this lane
        sup = (t >= 64) ? 0ull : (~0ull << t);
    }

    u32 seen = 0;
    if (wave != 0) {
        // ---- passive phase: consume published boxes until our turn (or done)
        for (;;) {
            u32 d  = __hip_atomic_load(&ctl[2], __ATOMIC_ACQUIRE, WG_SCOPE);
            u32 cn = __hip_atomic_load(&ctl[0], __ATOMIC_ACQUIRE, WG_SCOPE);
            bool prog = (seen < cn);
            while (seen < cn) {
                float4 bi = pubBox[seen]; seen++;
                float area_i = __fmul_rn(__fsub_rn(bi.z, bi.x), __fsub_rn(bi.w, bi.y));
                sup |= sweep_own<GE>(bi, area_i, breg, areaj, boxesLds, base, nslots, lane, B);
            }
            if (d) return;                                 // finished while passive
            u32 aw = __hip_atomic_load(&ctl[1], __ATOMIC_ACQUIRE, WG_SCOPE);
            if (aw == (u32)wave) {
                u32 cn2 = __hip_atomic_load(&ctl[0], __ATOMIC_ACQUIRE, WG_SCOPE);
                while (seen < cn2) {                       // final drain (cn2 is final)
                    float4 bi = pubBox[seen]; seen++;
                    float area_i = __fmul_rn(__fsub_rn(bi.z, bi.x), __fsub_rn(bi.w, bi.y));
                    sup |= sweep_own<GE>(bi, area_i, breg, areaj, boxesLds, base, nslots, lane, B);
                }
                break;                                     // become active
            }
            if (!prog) __builtin_amdgcn_s_sleep(1);
        }
    }

    // ---- active phase
    u32 nk = seen;
    int cursor = (base << 6) - 1;
    for (;;) {
        int js = cursor + 1;
        int s  = js >> 6;
        u64 bal = 0;
        if (s < end) {
            bal = __ballot((int)(((~sup) >> s) & 1ull)) & (~0ull << (js & 63));
            while (bal == 0) { s++; if (s >= end) break; bal = __ballot((int)(((~sup) >> s) & 1ull)); }
        }
        if (bal == 0) {                                    // range exhausted: hand off
            if (lane == 0) {
                if (wave == 3) __hip_atomic_store(&ctl[2], 1u, __ATOMIC_RELEASE, WG_SCOPE);
                else           __hip_atomic_store(&ctl[1], (u32)(wave + 1), __ATOMIC_RELEASE, WG_SCOPE);
            }
            return;
        }
        int i = (s << 6) + (int)__builtin_ctzll(bal);

        float4 bi = boxesLds[i];                           // uniform broadcast read
        float area_i = __fmul_rn(__fsub_rn(bi.z, bi.x), __fsub_rn(bi.w, bi.y));
        if (lane == 0) {
            pubBox[nk] = bi;
            keptR[nk]  = (u16)i;
            __hip_atomic_store(&ctl[0], nk + 1, __ATOMIC_RELEASE, WG_SCOPE);
        }
        nk++;
        if (nk >= KPC) {                                   // global top-300 can't need more
            if (lane == 0) __hip_atomic_store(&ctl[2], 1u, __ATOMIC_RELEASE, WG_SCOPE);
            return;
        }
        sup |= sweep_own<GE>(bi, area_i, breg, areaj, boxesLds, base, nslots, lane, B);
        cursor = i;
    }
}

// ---------------------------------------------------------------------------
// Per-class kernel.
// ---------------------------------------------------------------------------
__global__ __launch_bounds__(TPB, 1) void nms_class_kernel(
    const float* __restrict__ bboxes, const float* __restrict__ scores,
    const float* __restrict__ conf_ptr, const float* __restrict__ nms_ptr,
    int N, int C, u32* __restrict__ gidx, u64* __restrict__ gkept)
{
    __shared__ __align__(16) char smem[63860];
    u64*    sortbuf  = (u64*)smem;
    float4* boxesLds = (float4*)smem;
    u16*    keptR    = (u16*)(smem + 58368);
    u32*    ctl      = (u32*)(smem + 58976);
    float4* pubBox   = (float4*)(smem + 58992);
    int*    cntS     = (int*)(smem + 63856);

    const int tid = threadIdx.x;
    const int c   = blockIdx.x;               // fg class 0..nc-1
    const int cls = c + 1;
    const float conf = *conf_ptr;
    const float nmsT = *nms_ptr;

    // ---- phase 1: compact valid candidates. key = score_bits<<32 | idx
    // (desc sort of key == argsort(masked)[::-1] incl. tie order: larger idx first)
    if (tid == 0) *cntS = 0;
    __syncthreads();
    for (int i = tid; i < N; i += TPB) {
        float s = scores[(size_t)i * C + cls];
        if (s > conf) {
            int p = atomicAdd(cntS, 1);
            if (p < MSORT) sortbuf[p] = ((u64)__float_as_uint(s) << 32) | (u32)i;
        }
    }
    __syncthreads();
    int K = *cntS; if (K > BOXCAP) K = BOXCAP;
    for (int p = K + tid; p < MSORT; p += TPB) sortbuf[p] = 0;
    __syncthreads();

    // ---- phase 2: bitonic sort descending
    for (int kk = 2; kk <= MSORT; kk <<= 1) {
        for (int j = kk >> 1; j > 0; j >>= 1) {
            for (int i = tid; i < MSORT; i += TPB) {
                int ixj = i ^ j;
                if (ixj > i) {
                    u64 a = sortbuf[i], b = sortbuf[ixj];
                    if (((i & kk) == 0) ? (a < b) : (a > b)) { sortbuf[i] = b; sortbuf[ixj] = a; }
                }
            }
            __syncthreads();
        }
    }

    // ---- phase 3: keys -> registers; barrier; write gidx + gather boxes into
    // LDS (clobbers sortbuf). Garbage rows beyond K: their suppression bits
    // are pre-set / outside scanned ranges and never read.
    u32 myIdx[RPT];
    #pragma unroll
    for (int t = 0; t < RPT; t++) myIdx[t] = (u32)sortbuf[t * TPB + tid];
    __syncthreads();
    u32* gidx_c = gidx + (size_t)c * MSORT;
    #pragma unroll
    for (int t = 0; t < RPT; t++) {
        int r = t * TPB + tid;
        if (r < K) {
            u32 idx = myIdx[t];
            gidx_c[r] = idx;
            boxesLds[r] = ((const float4*)bboxes)[idx];
        }
    }
    if (tid == 0) { ctl[0] = 0; ctl[1] = 0; ctl[2] = 0; }
    __syncthreads();

    const int lane = tid & 63;
    const int wave = tid >> 6;

    // exact replacement for RN32(inter/uni) > T:  inter (cmp) B*uni in f64,
    // B = midpoint(T, nextafter(T)); cmp is >= iff nextafter(T) has even mantissa.
    const u32 tb = __float_as_uint(nmsT);
    const float Tn = __uint_as_float(tb + 1u);
    const double B = ((double)nmsT + (double)Tn) * 0.5;
    const bool geCmp = (((tb + 1u) & 1u) == 0u);

    const int smax = (K + 63) >> 6;            // <= 57
    if (geCmp) greedy_nms<true >(boxesLds, keptR, pubBox, ctl, K, smax, B, lane, wave);
    else       greedy_nms<false>(boxesLds, keptR, pubBox, ctl, K, smax, B, lane, wave);
    __syncthreads();                           // all waves done; keptR/cntK visible

    // ---- epilogue: build kept keys in parallel (all 256 threads)
    int kept = (int)ctl[0]; if (kept > KPC) kept = KPC;
    u64* gkept_c = gkept + (size_t)c * KPC;
    for (int p = tid; p < kept; p += TPB) {
        int rank = keptR[p];
        u32 idx  = gidx_c[rank];
        float sc = scores[(size_t)idx * C + cls];
        u32 flat = (u32)c * (u32)N + idx;      // top_k ties: lower flat first
        gkept_c[p] = ((u64)__float_as_uint(sc) << 32) | (u32)(~flat);
    }
    for (int p = kept + tid; p < KPC; p += TPB) gkept_c[p] = 0;
}

// ---------------------------------------------------------------------------
// Global top-Mout over nc*KPC kept keys: 2048-bin histogram select + 1024-slot
// LDS bitonic sort.
// ---------------------------------------------------------------------------
__global__ __launch_bounds__(1024) void nms_topk_kernel(
    const float* __restrict__ bboxes, const u64* __restrict__ gkept,
    int N, int nc, int Mout, float* __restrict__ out)
{
    __shared__ u32 hist[2048];
    __shared__ int chunk[64];
    __shared__ int selCount;
    __shared__ int bstarS;
    __shared__ u64 sel[SELCAP];

    const int tid = threadIdx.x;
    const int total = nc * KPC;

    for (int b = tid; b < 2048; b += 1024) hist[b] = 0;
    if (tid == 0) selCount = 0;
    __syncthreads();

    for (int t = tid; t < total; t += 1024) {
        u64 k = gkept[t];
        if (k) {
            int b = (int)((u32)(k >> 44)) - 0x3F000;
            b = b < 0 ? 0 : (b > 2047 ? 2047 : b);
            atomicAdd(&hist[b], 1u);
        }
    }
    __syncthreads();

    if (tid < 64) {
        int s = 0;
        #pragma unroll
        for (int b = 0; b < 32; b++) s += (int)hist[tid * 32 + b];
        chunk[tid] = s;
    }
    __syncthreads();

    if (tid == 0) {
        int acc = 0, ch = 63;
        for (; ch >= 0; ch--) {
            if (acc + chunk[ch] >= Mout) break;
            acc += chunk[ch];
        }
        int bs = 0;
        if (ch >= 0) {
            int b = (ch << 5) + 31;
            for (; b >= (ch << 5); b--) { acc += (int)hist[b]; if (acc >= Mout) break; }
            bs = (b < (ch << 5)) ? (ch << 5) : b;
        }
        bstarS = bs;
    }
    __syncthreads();
    const int bstar = bstarS;

    for (int t = tid; t < total; t += 1024) {
        u64 k = gkept[t];
        if (k) {
            int b = (int)((u32)(k >> 44)) - 0x3F000;
            b = b < 0 ? 0 : (b > 2047 ? 2047 : b);
            if (b >= bstar) {
                int p = atomicAdd(&selCount, 1);
                if (p < SELCAP) sel[p] = k;
            }
        }
    }
    __syncthreads();
    int cnt = selCount; if (cnt > SELCAP) cnt = SELCAP;
    for (int p = cnt + tid; p < SELCAP; p += 1024) sel[p] = 0;
    __syncthreads();

    for (int kk = 2; kk <= SELCAP; kk <<= 1) {
        for (int j = kk >> 1; j > 0; j >>= 1) {
            int i = tid;
            int ixj = i ^ j;
            if (i < SELCAP && ixj > i) {
                u64 a = sel[i], b = sel[ixj];
                if (((i & kk) == 0) ? (a < b) : (a > b)) { sel[i] = b; sel[ixj] = a; }
            }
            __syncthreads();
        }
    }

    for (int t = tid; t < Mout; t += 1024) {
        u64 k = (t < SELCAP) ? sel[t] : 0;
        float px1 = 0.f, py1 = 0.f, px2 = 0.f, py2 = 0.f, ps = 0.f, plab = -1.0f;
        if (k) {
            float s  = __uint_as_float((u32)(k >> 32));
            u32 flat = ~((u32)k);
            int cc   = (int)(flat / (u32)N);
            int box  = (int)(flat - (u32)cc * (u32)N);
            float4 bb = ((const float4*)bboxes)[box];
            px1 = bb.x; py1 = bb.y; px2 = bb.z; py2 = bb.w; ps = s;
            plab = (float)(cc + 1);
        }
        out[t * 5 + 0] = px1;
        out[t * 5 + 1] = py1;
        out[t * 5 + 2] = px2;
        out[t * 5 + 3] = py2;
        out[t * 5 + 4] = ps;
        out[Mout * 5 + t] = plab;
    }
}

extern "C" void kernel_launch(void* const* d_in, const int* in_sizes, int n_in,
                              void* d_out, int out_size, void* d_ws, size_t ws_size,
                              hipStream_t stream) {
    const float* bboxes = (const float*)d_in[0];
    const float* scores = (const float*)d_in[1];
    const float* conf   = (const float*)d_in[2];
    const float* nmsT   = (const float*)d_in[3];

    const int N    = in_sizes[0] / 4;        // 5000
    const int C    = in_sizes[1] / N;        // 81
    const int nc   = C - 1;                  // 80
    const int Mout = out_size / 6;           // 300

    // ws layout: [gidx: nc*MSORT u32 = 1.31 MB][gkept: nc*KPC u64 = 192 KB]
    u32* gidx  = (u32*)d_ws;
    u64* gkept = (u64*)((char*)d_ws + (size_t)nc * MSORT * sizeof(u32));

    nms_class_kernel<<<nc, TPB, 0, stream>>>(bboxes, scores, conf, nmsT, N, C, gidx, gkept);
    nms_topk_kernel<<<1, 1024, 0, stream>>>(bboxes, gkept, N, nc, Mout, (float*)d_out);
}